// Round 1
// 482.107 us; speedup vs baseline: 1.3371x; 1.3371x over previous
//
#include <hip/hip_runtime.h>
#include <stdint.h>

// L=S=1024, N=16, E=1024, single head. f32 in/out, bf16 MFMA internally.
//
// R5: deep-pipelined 256x256 GEMM engine (catalog T2+T3/T4+T5):
//   - BK=32, ring of 4 LDS buffers (128 KiB), global_load_lds staging 3 tiles
//     ahead, counted s_waitcnt vmcnt(8) once per K-tile (never 0 in loop).
//   - 512 thr / 8 waves (2Mx4N), wave tile 128x64, 2 phases x 16 MFMA per tile,
//     raw s_barrier + s_setprio(1) around MFMA.
//   - LDS XOR swizzle on 16B chunks: p = c ^ ((c>>3)&7)  (involution; bits>=3
//     unchanged). Store side: linear LDS dest + pre-swizzled per-lane global
//     source. Read side: lane-constant offset ((lr*4+q4)^((lr>>1)&7))*16B.
//     2-way max bank aliasing (free per m136).
// Pipeline: cvt Q,Wq -> Qproj ; cvt K,Wk -> Kproj ; scores ; softmax ;
//           cvt V,Wv -> Vt (= Wv*V^T + bv, row-bias GEMM, replaces proj+transpose) ; PV.
// Buffers (32MB regions): WSA,WSB = d_ws ; OC,OD = d_out halves.
//   Qproj->OC, Kproj->OD, scores/attn->WSB, Vt->WSA, out->d_out (all inputs dead).

typedef __attribute__((ext_vector_type(8))) short bf16x8;   // 8 bf16 = 4 VGPRs
typedef __attribute__((ext_vector_type(4))) float f32x4;    // MFMA 16x16 accum

__device__ __forceinline__ float bf2f(unsigned short u) {
    union { unsigned int i; float f; } w; w.i = ((unsigned int)u) << 16; return w.f;
}
__device__ __forceinline__ unsigned short f2bf(float f) {
    union { float f; unsigned int i; } w; w.f = f;
    unsigned int r = (w.i + 0x7FFFu + ((w.i >> 16) & 1u)) >> 16;  // RNE
    return (unsigned short)r;
}

// async global->LDS, 16B/lane; LDS dest is wave-uniform base + lane*16B
__device__ __forceinline__ void g2l16(const unsigned short* g, unsigned short* l) {
    __builtin_amdgcn_global_load_lds(
        (const __attribute__((address_space(1))) unsigned int*)g,
        (__attribute__((address_space(3))) unsigned int*)l, 16, 0, 0);
}

#define BM 256
#define BN 256
#define BK 32

// C[m][col] = (sum_k A[m,k]*B[col,k] + bias) * scale.
// BIAS_MODE: 0 none, 1 per-col, 2 per-row. K must be a multiple of 32, K/32 >= 4.
template <int BIAS_MODE, typename OutT>
__global__ __launch_bounds__(512, 2) void gemm_bt2(
    const unsigned short* __restrict__ A,
    const unsigned short* __restrict__ B,
    OutT* __restrict__ C,
    const float* __restrict__ bias,
    float scale, int K,
    long lda, long ldb, long ldc,
    long aBatch, long bBatch, long cBatch,
    int gridM, int gridN)
{
    // ring: buf*16384 shorts; A tile at +0 (8192), B tile at +8192.
    __shared__ __align__(16) unsigned short lds[65536];   // 128 KiB

    const int tid  = threadIdx.x;
    const int wave = tid >> 6;      // 0..7
    const int lane = tid & 63;
    const int lr   = lane & 15;
    const int q4   = lane >> 4;
    const int wm   = wave >> 2;     // 0..1  (M half)
    const int wn   = wave & 3;      // 0..3  (N quarter)

    const int per  = gridM * gridN;
    const int bid  = blockIdx.x;
    const int bz   = bid / per;
    const int rem  = bid - bz * per;
    const int brow = rem % gridM;   // row-fast: A-panel sharers land on same XCD
    const int bcol = rem / gridM;
    const long m0 = (long)brow * BM;
    const long n0 = (long)bcol * BN;
    A += (long)bz * aBatch;
    B += (long)bz * bBatch;
    C += (long)bz * cBatch;

    // ---- staging map: physical chunk pc = i*512 + tid holds logical chunk
    //      lc = pc ^ ((pc>>3)&7); row = lc>>2 (+i*128), k16 = lc&3.
    const int tswz  = tid ^ ((tid >> 3) & 7);
    const int srow  = tswz >> 2;          // 0..127
    const int skoff = (tswz & 3) * 8;     // element offset in k
    const unsigned short* aS0 = A + (m0 + srow) * lda + skoff;
    const unsigned short* aS1 = A + (m0 + 128 + srow) * lda + skoff;
    const unsigned short* bS0 = B + (n0 + srow) * ldb + skoff;
    const unsigned short* bS1 = B + (n0 + 128 + srow) * ldb + skoff;
    const int ldsW = wave * 512;          // wave's 1KB slice within a stage inst

    // ---- swizzled fragment read offset (lane constant, in ushorts)
    const int myoff = (((lr << 2) | q4) ^ ((lr >> 1) & 7)) << 3;

    f32x4 acc[8][4];
    const f32x4 zero = {0.f, 0.f, 0.f, 0.f};
#pragma unroll
    for (int m = 0; m < 8; m++)
#pragma unroll
        for (int n = 0; n < 4; n++) acc[m][n] = zero;

    const int nkt = K / BK;   // 32 here

    // ---- prologue: stage tiles 0..2 into bufs 0..2 (12 loads)
#pragma unroll
    for (int t = 0; t < 3; t++) {
        const long kb = (long)t * BK;
        unsigned short* base = &lds[t * 16384];
        g2l16(aS0 + kb, base + ldsW);
        g2l16(aS1 + kb, base + 4096 + ldsW);
        g2l16(bS0 + kb, base + 8192 + ldsW);
        g2l16(bS1 + kb, base + 12288 + ldsW);
    }
    asm volatile("s_waitcnt vmcnt(8)" ::: "memory");   // tile 0 landed (per wave)
    __builtin_amdgcn_s_barrier();                      // ... for every wave

    for (int kt = 0; kt < nkt; kt++) {
        const int buf  = kt & 3;
        const int sbuf = (kt + 3) & 3;                       // == (kt-1)&3: read-retired last iter
        const int st   = (kt + 3 < nkt) ? kt + 3 : nkt - 1;  // clamp: dummy re-stage keeps vmcnt uniform
        const long kb  = (long)st * BK;
        const unsigned short* At = &lds[buf * 16384];
        const unsigned short* Bt = At + 8192;
        unsigned short* sb = &lds[sbuf * 16384];

        // ======== phase 0: A m0-3 + B n0-3 frags; stage A of tile kt+3 ========
        bf16x8 af[4], bfr[4];
#pragma unroll
        for (int m = 0; m < 4; m++)
            af[m] = *(const bf16x8*)&At[(wm * 128 + m * 16) * 32 + myoff];
#pragma unroll
        for (int n = 0; n < 4; n++)
            bfr[n] = *(const bf16x8*)&Bt[(wn * 64 + n * 16) * 32 + myoff];
        g2l16(aS0 + kb, sb + ldsW);
        g2l16(aS1 + kb, sb + 4096 + ldsW);
        __builtin_amdgcn_s_barrier();
        __builtin_amdgcn_s_setprio(1);
#pragma unroll
        for (int m = 0; m < 4; m++)
#pragma unroll
            for (int n = 0; n < 4; n++)
                acc[m][n] = __builtin_amdgcn_mfma_f32_16x16x32_bf16(
                    af[m], bfr[n], acc[m][n], 0, 0, 0);
        __builtin_amdgcn_s_setprio(0);
        __builtin_amdgcn_s_barrier();

        // ======== phase 1: A m4-7 frags (B reused); stage B of tile kt+3 ========
        bf16x8 ag[4];
#pragma unroll
        for (int m = 0; m < 4; m++)
            ag[m] = *(const bf16x8*)&At[(wm * 128 + 64 + m * 16) * 32 + myoff];
        g2l16(bS0 + kb, sb + 8192 + ldsW);
        g2l16(bS1 + kb, sb + 12288 + ldsW);
        __builtin_amdgcn_s_barrier();
        __builtin_amdgcn_s_setprio(1);
#pragma unroll
        for (int m = 0; m < 4; m++)
#pragma unroll
            for (int n = 0; n < 4; n++)
                acc[4 + m][n] = __builtin_amdgcn_mfma_f32_16x16x32_bf16(
                    ag[m], bfr[n], acc[4 + m][n], 0, 0, 0);
        __builtin_amdgcn_s_setprio(0);
        // counted boundary wait: allow iters kt-? .. in-flight tiles kt+2,kt+3 (8 loads);
        // guarantees tile kt+1 (staged 2 iters ago) fully landed for every wave.
        asm volatile("s_waitcnt vmcnt(8)" ::: "memory");
        __builtin_amdgcn_s_barrier();
        __builtin_amdgcn_sched_barrier(0);
    }

    // ---- epilogue: verified C/D map: col = lane&15, row = q4*4 + reg.
#pragma unroll
    for (int n = 0; n < 4; n++) {
        const long col = n0 + wn * 64 + n * 16 + lr;
        float cb = 0.f;
        if constexpr (BIAS_MODE == 1) cb = bias[col];
#pragma unroll
        for (int m = 0; m < 8; m++) {
            const long row = m0 + wm * 128 + m * 16 + q4 * 4;
#pragma unroll
            for (int r = 0; r < 4; r++) {
                float v = acc[m][n][r];
                if constexpr (BIAS_MODE == 1) v += cb;
                if constexpr (BIAS_MODE == 2) v += bias[row + r];
                v *= scale;
                if constexpr (sizeof(OutT) == 2)
                    C[(row + r) * ldc + col] = (OutT)f2bf(v);
                else
                    C[(row + r) * ldc + col] = v;
            }
        }
    }
}

// f32 -> bf16 (RNE), 8 elements/thread/iter, grid-stride. n8 = elements/8.
__global__ __launch_bounds__(256) void cvt_f32_bf16(
    const float* __restrict__ in, unsigned short* __restrict__ out, long n8)
{
    const long stride = (long)gridDim.x * blockDim.x;
    for (long i = (long)blockIdx.x * blockDim.x + threadIdx.x; i < n8; i += stride) {
        const float4* p = (const float4*)(in + i * 8);
        float4 a = p[0], b = p[1];
        bf16x8 v;
        v[0] = (short)f2bf(a.x); v[1] = (short)f2bf(a.y);
        v[2] = (short)f2bf(a.z); v[3] = (short)f2bf(a.w);
        v[4] = (short)f2bf(b.x); v[5] = (short)f2bf(b.y);
        v[6] = (short)f2bf(b.z); v[7] = (short)f2bf(b.w);
        *(bf16x8*)(out + i * 8) = v;
    }
}

// In-place softmax on rows of 1024 bf16; f32 math; clamp keeps failures finite.
__global__ __launch_bounds__(256) void softmax_rows(unsigned short* __restrict__ base)
{
    unsigned short* p = base + (long)blockIdx.x * 1024;
    const int tid = threadIdx.x;
    ushort4 u = ((const ushort4*)p)[tid];
    float x0 = bf2f(u.x), x1 = bf2f(u.y), x2 = bf2f(u.z), x3 = bf2f(u.w);
    x0 = fminf(fmaxf(x0, -1e30f), 1e30f);
    x1 = fminf(fmaxf(x1, -1e30f), 1e30f);
    x2 = fminf(fmaxf(x2, -1e30f), 1e30f);
    x3 = fminf(fmaxf(x3, -1e30f), 1e30f);

    float m = fmaxf(fmaxf(x0, x1), fmaxf(x2, x3));
#pragma unroll
    for (int o = 32; o > 0; o >>= 1) m = fmaxf(m, __shfl_xor(m, o));
    __shared__ float redm[4], reds[4];
    const int wave = tid >> 6, lane = tid & 63;
    if (lane == 0) redm[wave] = m;
    __syncthreads();
    m = fmaxf(fmaxf(redm[0], redm[1]), fmaxf(redm[2], redm[3]));

    float e0 = __expf(x0 - m), e1 = __expf(x1 - m);
    float e2 = __expf(x2 - m), e3 = __expf(x3 - m);
    float s = e0 + e1 + e2 + e3;
#pragma unroll
    for (int o = 32; o > 0; o >>= 1) s += __shfl_xor(s, o);
    if (lane == 0) reds[wave] = s;
    __syncthreads();
    s = reds[0] + reds[1] + reds[2] + reds[3];
    const float inv = 1.0f / s;

    ushort4 ov = make_ushort4(f2bf(e0 * inv), f2bf(e1 * inv),
                              f2bf(e2 * inv), f2bf(e3 * inv));
    ((ushort4*)p)[tid] = ov;
}

extern "C" void kernel_launch(void* const* d_in, const int* in_sizes, int n_in,
                              void* d_out, int out_size, void* d_ws, size_t ws_size,
                              hipStream_t stream) {
    const float* query = (const float*)d_in[0];  // (1024,16,1024) f32, rows l*16+n
    const float* keyp  = (const float*)d_in[1];  // rows s*16+n
    const float* valp  = (const float*)d_in[2];
    const float* wq    = (const float*)d_in[3];  // (1024,1024) f32
    const float* wk    = (const float*)d_in[4];
    const float* wv    = (const float*)d_in[5];
    const float* bias  = (const float*)d_in[6];  // (3072,) f32
    float* out = (float*)d_out;                  // 16M f32 = 64 MB

    unsigned short* WSA = (unsigned short*)d_ws;  // 32 MB
    unsigned short* WSB = WSA + 16777216;         // 32 MB
    unsigned short* OC  = (unsigned short*)d_out; // 32 MB (dead before final PV write)
    unsigned short* OD  = OC + 16777216;          // 32 MB

    const dim3 cblk(256, 1, 1);
    const dim3 gblk(512, 1, 1);

    // 1) Q -> bf16 (WSA); Wq -> bf16 (WSB[0:2MB))
    cvt_f32_bf16<<<2048, cblk, 0, stream>>>(query, WSA, 2097152);
    cvt_f32_bf16<<<512, cblk, 0, stream>>>(wq, WSB, 131072);
    // 2) Qproj = (Q @ Wq^T + bq) * E^-0.5 -> OC (bf16, rows l*16+n)
    gemm_bt2<1, unsigned short><<<256, gblk, 0, stream>>>(
        WSA, WSB, OC, bias, 0.03125f, 1024,
        1024, 1024, 1024, 0, 0, 0, 64, 4);
    // 3) K -> bf16 (WSA); Wk -> bf16 (WSB)
    cvt_f32_bf16<<<2048, cblk, 0, stream>>>(keyp, WSA, 2097152);
    cvt_f32_bf16<<<512, cblk, 0, stream>>>(wk, WSB, 131072);
    // 4) Kproj = K @ Wk^T + bk -> OD (bf16, rows s*16+n)
    gemm_bt2<1, unsigned short><<<256, gblk, 0, stream>>>(
        WSA, WSB, OD, bias + 1024, 1.0f, 1024,
        1024, 1024, 1024, 0, 0, 0, 64, 4);
    // 5) scores[n][l][s] = Qproj_n @ Kproj_n^T -> WSB (Wkb region dead)
    gemm_bt2<0, unsigned short><<<256, gblk, 0, stream>>>(
        OC, OD, WSB, nullptr, 1.0f, 1024,
        16384, 16384, 1024, 1024, 1024, 1048576, 4, 4);
    // 6) softmax over s, all 16384 rows, in place
    softmax_rows<<<16384, cblk, 0, stream>>>(WSB);
    // 7) V -> bf16 (OC; Qproj dead); Wv -> bf16 (OD[0:2MB); Kproj dead)
    cvt_f32_bf16<<<2048, cblk, 0, stream>>>(valp, OC, 2097152);
    cvt_f32_bf16<<<512, cblk, 0, stream>>>(wv, OD, 131072);
    // 8) Vt[n][f][s] = Wv @ V_n^T + bv[f] (row-bias; replaces Vproj+transpose) -> WSA
    gemm_bt2<2, unsigned short><<<256, gblk, 0, stream>>>(
        OD, OC, WSA, bias + 2048, 1.0f, 1024,
        1024, 16384, 1024, 0, 1024, 1048576, 4, 4);
    // 9) out[(l*16+n)][f] = attn_n[l][:] . Vt_n[f][:] -> d_out (f32; V16/Wvb dead)
    gemm_bt2<0, float><<<256, gblk, 0, stream>>>(
        WSB, WSA, out, nullptr, 1.0f, 1024,
        1024, 1024, 16384, 1048576, 1048576, 1024, 4, 4);
}

// Round 2
// 430.834 us; speedup vs baseline: 1.4962x; 1.1190x over previous
//
#include <hip/hip_runtime.h>
#include <stdint.h>

// L=S=1024, N=16, E=1024, single head. f32 in/out, bf16 MFMA internally.
//
// R6 = R5 K-loop (unchanged: BK=32 ring-4 LDS, counted vmcnt(8), 2 phases x
// 16 MFMA, raw barriers, setprio) plus:
//   1. LDS-staged coalesced epilogue: acc -> LDS (q4-XOR swizzled, conflict
//      free) -> 16B/lane full-line global stores. Kills the 2x write
//      amplification (WRITE_SIZE 66MB -> ~34MB) and the scattered-2B tail.
//      f32 output in two 128-row passes (256KB > 128KB LDS).
//   2. Bijective chunked XCD swizzle (grid==256 always): l=(p&7)*32+(p>>3),
//      bcol-fast decode -> panel sharers co-resident per XCD L2.
//   3. Fused dual-tensor cvt kernels: 12 -> 9 dispatches.

typedef __attribute__((ext_vector_type(8))) short bf16x8;   // 8 bf16 = 4 VGPRs
typedef __attribute__((ext_vector_type(4))) float f32x4;    // MFMA 16x16 accum

__device__ __forceinline__ float bf2f(unsigned short u) {
    union { unsigned int i; float f; } w; w.i = ((unsigned int)u) << 16; return w.f;
}
__device__ __forceinline__ unsigned short f2bf(float f) {
    union { float f; unsigned int i; } w; w.f = f;
    unsigned int r = (w.i + 0x7FFFu + ((w.i >> 16) & 1u)) >> 16;  // RNE
    return (unsigned short)r;
}

// async global->LDS, 16B/lane; LDS dest is wave-uniform base + lane*16B
__device__ __forceinline__ void g2l16(const unsigned short* g, unsigned short* l) {
    __builtin_amdgcn_global_load_lds(
        (const __attribute__((address_space(1))) unsigned int*)g,
        (__attribute__((address_space(3))) unsigned int*)l, 16, 0, 0);
}

#define BM 256
#define BN 256
#define BK 32

// C[m][col] = (sum_k A[m,k]*B[col,k] + bias) * scale.
// BIAS_MODE: 0 none, 1 per-col, 2 per-row. K multiple of 32, K/32 >= 4.
// Grid MUST be exactly 256 blocks (8 XCDs x 32 chunk).
template <int BIAS_MODE, typename OutT>
__global__ __launch_bounds__(512, 2) void gemm_bt2(
    const unsigned short* __restrict__ A,
    const unsigned short* __restrict__ B,
    OutT* __restrict__ C,
    const float* __restrict__ bias,
    float scale, int K,
    long lda, long ldb, long ldc,
    long aBatch, long bBatch, long cBatch,
    int gridM, int gridN)
{
    // K-loop: ring of 4 x (A 8K + B 8K shorts). Epilogue reuses all 128KB.
    __shared__ __align__(16) unsigned short lds[65536];   // 128 KiB

    const int tid  = threadIdx.x;
    const int wave = tid >> 6;      // 0..7
    const int lane = tid & 63;
    const int lr   = lane & 15;
    const int q4   = lane >> 4;
    const int wm   = wave >> 2;     // 0..1  (M half)
    const int wn   = wave & 3;      // 0..3  (N quarter)

    // chunked XCD swizzle: physical p -> logical l; XCD (p%8) owns l in
    // [x*32, x*32+32). bcol-fast decode: A-panel sharers (same brow) and
    // B-panel sharers stay within one XCD's chunk.
    const int p    = blockIdx.x;
    const int l    = ((p & 7) << 5) + (p >> 3);
    const int bcol = l % gridN;
    const int t2   = l / gridN;
    const int brow = t2 % gridM;
    const int bz   = t2 / gridM;

    const long m0 = (long)brow * BM;
    const long n0 = (long)bcol * BN;
    A += (long)bz * aBatch;
    B += (long)bz * bBatch;
    C += (long)bz * cBatch;

    // ---- staging map: physical chunk pc = i*512 + tid holds logical chunk
    //      lc = pc ^ ((pc>>3)&7); row = lc>>2 (+i*128), k16 = lc&3.
    const int tswz  = tid ^ ((tid >> 3) & 7);
    const int srow  = tswz >> 2;          // 0..127
    const int skoff = (tswz & 3) * 8;     // element offset in k
    const unsigned short* aS0 = A + (m0 + srow) * lda + skoff;
    const unsigned short* aS1 = A + (m0 + 128 + srow) * lda + skoff;
    const unsigned short* bS0 = B + (n0 + srow) * ldb + skoff;
    const unsigned short* bS1 = B + (n0 + 128 + srow) * ldb + skoff;
    const int ldsW = wave * 512;          // wave's 1KB slice within a stage inst

    // ---- swizzled fragment read offset (lane constant, in ushorts)
    const int myoff = (((lr << 2) | q4) ^ ((lr >> 1) & 7)) << 3;

    f32x4 acc[8][4];
    const f32x4 zero = {0.f, 0.f, 0.f, 0.f};
#pragma unroll
    for (int m = 0; m < 8; m++)
#pragma unroll
        for (int n = 0; n < 4; n++) acc[m][n] = zero;

    const int nkt = K / BK;   // 32 here

    // ---- prologue: stage tiles 0..2 into bufs 0..2 (12 loads)
#pragma unroll
    for (int t = 0; t < 3; t++) {
        const long kb = (long)t * BK;
        unsigned short* base = &lds[t * 16384];
        g2l16(aS0 + kb, base + ldsW);
        g2l16(aS1 + kb, base + 4096 + ldsW);
        g2l16(bS0 + kb, base + 8192 + ldsW);
        g2l16(bS1 + kb, base + 12288 + ldsW);
    }
    asm volatile("s_waitcnt vmcnt(8)" ::: "memory");   // tile 0 landed (per wave)
    __builtin_amdgcn_s_barrier();                      // ... for every wave

    for (int kt = 0; kt < nkt; kt++) {
        const int buf  = kt & 3;
        const int sbuf = (kt + 3) & 3;                       // read-retired last iter
        const int st   = (kt + 3 < nkt) ? kt + 3 : nkt - 1;  // clamp: dummy re-stage
        const long kb  = (long)st * BK;
        const unsigned short* At = &lds[buf * 16384];
        const unsigned short* Bt = At + 8192;
        unsigned short* sb = &lds[sbuf * 16384];

        // ======== phase 0: A m0-3 + B n0-3 frags; stage A of tile kt+3 ========
        bf16x8 af[4], bfr[4];
#pragma unroll
        for (int m = 0; m < 4; m++)
            af[m] = *(const bf16x8*)&At[(wm * 128 + m * 16) * 32 + myoff];
#pragma unroll
        for (int n = 0; n < 4; n++)
            bfr[n] = *(const bf16x8*)&Bt[(wn * 64 + n * 16) * 32 + myoff];
        g2l16(aS0 + kb, sb + ldsW);
        g2l16(aS1 + kb, sb + 4096 + ldsW);
        __builtin_amdgcn_s_barrier();
        __builtin_amdgcn_s_setprio(1);
#pragma unroll
        for (int m = 0; m < 4; m++)
#pragma unroll
            for (int n = 0; n < 4; n++)
                acc[m][n] = __builtin_amdgcn_mfma_f32_16x16x32_bf16(
                    af[m], bfr[n], acc[m][n], 0, 0, 0);
        __builtin_amdgcn_s_setprio(0);
        __builtin_amdgcn_s_barrier();

        // ======== phase 1: A m4-7 frags (B reused); stage B of tile kt+3 ========
        bf16x8 ag[4];
#pragma unroll
        for (int m = 0; m < 4; m++)
            ag[m] = *(const bf16x8*)&At[(wm * 128 + 64 + m * 16) * 32 + myoff];
        g2l16(bS0 + kb, sb + 8192 + ldsW);
        g2l16(bS1 + kb, sb + 12288 + ldsW);
        __builtin_amdgcn_s_barrier();
        __builtin_amdgcn_s_setprio(1);
#pragma unroll
        for (int m = 0; m < 4; m++)
#pragma unroll
            for (int n = 0; n < 4; n++)
                acc[4 + m][n] = __builtin_amdgcn_mfma_f32_16x16x32_bf16(
                    ag[m], bfr[n], acc[4 + m][n], 0, 0, 0);
        __builtin_amdgcn_s_setprio(0);
        // counted boundary wait: tiles kt+2,kt+3 (8 loads) may stay in flight;
        // guarantees tile kt+1 fully landed for every wave.
        asm volatile("s_waitcnt vmcnt(8)" ::: "memory");
        __builtin_amdgcn_s_barrier();
        __builtin_amdgcn_sched_barrier(0);
    }

    // ==================== LDS-staged coalesced epilogue ====================
    // Drain dummy re-stage DMAs before reusing LDS.
    asm volatile("s_waitcnt vmcnt(0)" ::: "memory");
    __syncthreads();

    if constexpr (sizeof(OutT) == 2) {
        // bf16: whole 256x256 tile fits (128KB). q4-XOR swizzle: one
        // ds_write_b16 hits 4 q4-rows; XOR ((row>>2)&3)<<4 (ushorts = 32B)
        // spreads them across the full 128B bank sweep -> conflict-free.
#pragma unroll
        for (int m = 0; m < 8; m++)
#pragma unroll
            for (int n = 0; n < 4; n++) {
                const int col = wn * 64 + n * 16 + lr;
#pragma unroll
                for (int r = 0; r < 4; r++) {
                    const int row = wm * 128 + m * 16 + q4 * 4 + r;
                    float v = acc[m][n][r];
                    if constexpr (BIAS_MODE == 1) v += bias[n0 + col];
                    if constexpr (BIAS_MODE == 2) v += bias[m0 + row];
                    v *= scale;
                    lds[row * 256 + (col ^ (((row >> 2) & 3) << 4))] = f2bf(v);
                }
            }
        __syncthreads();
        // 16 sweeps x 8KB: per wave 2 full 512B row-segments, 16B/lane.
#pragma unroll
        for (int i = 0; i < 16; i++) {
            const int g   = i * 512 + tid;
            const int row = g >> 5;
            const int ch  = g & 31;
            bf16x8 v = *(const bf16x8*)&lds[row * 256 + ((ch * 8) ^ (((row >> 2) & 3) << 4))];
            *(bf16x8*)((unsigned short*)C + (m0 + row) * ldc + n0 + ch * 8) = v;
        }
    } else {
        // f32: two 128-row passes (each 128KB).
        float* fl = (float*)lds;
#pragma unroll
        for (int h = 0; h < 2; h++) {
            __syncthreads();
            if (wm == h) {
#pragma unroll
                for (int m = 0; m < 8; m++)
#pragma unroll
                    for (int n = 0; n < 4; n++) {
                        const int col = wn * 64 + n * 16 + lr;
#pragma unroll
                        for (int r = 0; r < 4; r++) {
                            const int rowh = m * 16 + q4 * 4 + r;   // 0..127
                            float v = acc[m][n][r];
                            if constexpr (BIAS_MODE == 1) v += bias[n0 + col];
                            if constexpr (BIAS_MODE == 2) v += bias[m0 + h * 128 + rowh];
                            v *= scale;
                            fl[rowh * 256 + (col ^ (((rowh >> 2) & 3) << 4))] = v;
                        }
                    }
            }
            __syncthreads();
#pragma unroll
            for (int i = 0; i < 16; i++) {
                const int g   = i * 512 + tid;
                const int row = g >> 6;          // 64 x 16B chunks per 1KB row
                const int ch  = g & 63;
                float4 v = *(const float4*)&fl[row * 256 + ((ch * 4) ^ (((row >> 2) & 3) << 4))];
                *(float4*)((float*)C + (m0 + h * 128 + row) * ldc + n0 + ch * 4) = v;
            }
        }
    }
}

// Fused dual-tensor f32 -> bf16 (RNE), 8 elem/thread/iter, grid-stride.
__global__ __launch_bounds__(256) void cvt2_f32_bf16(
    const float* __restrict__ inA, unsigned short* __restrict__ outA, long n8A,
    const float* __restrict__ inB, unsigned short* __restrict__ outB, long n8B)
{
    const long total  = n8A + n8B;
    const long stride = (long)gridDim.x * blockDim.x;
    for (long i = (long)blockIdx.x * blockDim.x + threadIdx.x; i < total; i += stride) {
        const float* src;
        unsigned short* dst;
        long j;
        if (i < n8A) { src = inA; dst = outA; j = i; }
        else         { src = inB; dst = outB; j = i - n8A; }
        const float4* pp = (const float4*)(src + j * 8);
        float4 a = pp[0], b = pp[1];
        bf16x8 v;
        v[0] = (short)f2bf(a.x); v[1] = (short)f2bf(a.y);
        v[2] = (short)f2bf(a.z); v[3] = (short)f2bf(a.w);
        v[4] = (short)f2bf(b.x); v[5] = (short)f2bf(b.y);
        v[6] = (short)f2bf(b.z); v[7] = (short)f2bf(b.w);
        *(bf16x8*)(dst + j * 8) = v;
    }
}

// In-place softmax on rows of 1024 bf16; f32 math; clamp keeps failures finite.
__global__ __launch_bounds__(256) void softmax_rows(unsigned short* __restrict__ base)
{
    unsigned short* p = base + (long)blockIdx.x * 1024;
    const int tid = threadIdx.x;
    ushort4 u = ((const ushort4*)p)[tid];
    float x0 = bf2f(u.x), x1 = bf2f(u.y), x2 = bf2f(u.z), x3 = bf2f(u.w);
    x0 = fminf(fmaxf(x0, -1e30f), 1e30f);
    x1 = fminf(fmaxf(x1, -1e30f), 1e30f);
    x2 = fminf(fmaxf(x2, -1e30f), 1e30f);
    x3 = fminf(fmaxf(x3, -1e30f), 1e30f);

    float m = fmaxf(fmaxf(x0, x1), fmaxf(x2, x3));
#pragma unroll
    for (int o = 32; o > 0; o >>= 1) m = fmaxf(m, __shfl_xor(m, o));
    __shared__ float redm[4], reds[4];
    const int wave = tid >> 6, lane = tid & 63;
    if (lane == 0) redm[wave] = m;
    __syncthreads();
    m = fmaxf(fmaxf(redm[0], redm[1]), fmaxf(redm[2], redm[3]));

    float e0 = __expf(x0 - m), e1 = __expf(x1 - m);
    float e2 = __expf(x2 - m), e3 = __expf(x3 - m);
    float s = e0 + e1 + e2 + e3;
#pragma unroll
    for (int o = 32; o > 0; o >>= 1) s += __shfl_xor(s, o);
    if (lane == 0) reds[wave] = s;
    __syncthreads();
    s = reds[0] + reds[1] + reds[2] + reds[3];
    const float inv = 1.0f / s;

    ushort4 ov = make_ushort4(f2bf(e0 * inv), f2bf(e1 * inv),
                              f2bf(e2 * inv), f2bf(e3 * inv));
    ((ushort4*)p)[tid] = ov;
}

extern "C" void kernel_launch(void* const* d_in, const int* in_sizes, int n_in,
                              void* d_out, int out_size, void* d_ws, size_t ws_size,
                              hipStream_t stream) {
    const float* query = (const float*)d_in[0];  // (1024,16,1024) f32, rows l*16+n
    const float* keyp  = (const float*)d_in[1];  // rows s*16+n
    const float* valp  = (const float*)d_in[2];
    const float* wq    = (const float*)d_in[3];  // (1024,1024) f32
    const float* wk    = (const float*)d_in[4];
    const float* wv    = (const float*)d_in[5];
    const float* bias  = (const float*)d_in[6];  // (3072,) f32
    float* out = (float*)d_out;                  // 16M f32 = 64 MB

    unsigned short* WSA = (unsigned short*)d_ws;  // 32 MB
    unsigned short* WSB = WSA + 16777216;         // 32 MB
    unsigned short* OC  = (unsigned short*)d_out; // 32 MB (dead before final PV write)
    unsigned short* OD  = OC + 16777216;          // 32 MB

    const dim3 cblk(256, 1, 1);
    const dim3 gblk(512, 1, 1);

    // 1) Q -> bf16 (WSA) + Wq -> bf16 (WSB[0:2MB)) fused
    cvt2_f32_bf16<<<2048, cblk, 0, stream>>>(query, WSA, 2097152, wq, WSB, 131072);
    // 2) Qproj = (Q @ Wq^T + bq) * E^-0.5 -> OC (bf16, rows l*16+n)
    gemm_bt2<1, unsigned short><<<256, gblk, 0, stream>>>(
        WSA, WSB, OC, bias, 0.03125f, 1024,
        1024, 1024, 1024, 0, 0, 0, 64, 4);
    // 3) K -> bf16 (WSA) + Wk -> bf16 (WSB) fused
    cvt2_f32_bf16<<<2048, cblk, 0, stream>>>(keyp, WSA, 2097152, wk, WSB, 131072);
    // 4) Kproj = K @ Wk^T + bk -> OD (bf16, rows s*16+n)
    gemm_bt2<1, unsigned short><<<256, gblk, 0, stream>>>(
        WSA, WSB, OD, bias + 1024, 1.0f, 1024,
        1024, 1024, 1024, 0, 0, 0, 64, 4);
    // 5) scores[n][l][s] = Qproj_n @ Kproj_n^T -> WSB
    gemm_bt2<0, unsigned short><<<256, gblk, 0, stream>>>(
        OC, OD, WSB, nullptr, 1.0f, 1024,
        16384, 16384, 1024, 1024, 1024, 1048576, 4, 4);
    // 6) softmax over s, all 16384 rows, in place
    softmax_rows<<<16384, cblk, 0, stream>>>(WSB);
    // 7) V -> bf16 (OC; Qproj dead) + Wv -> bf16 (OD[0:2MB); Kproj dead) fused
    cvt2_f32_bf16<<<2048, cblk, 0, stream>>>(valp, OC, 2097152, wv, OD, 131072);
    // 8) Vt[n][f][s] = Wv @ V_n^T + bv[f] (row-bias) -> WSA
    gemm_bt2<2, unsigned short><<<256, gblk, 0, stream>>>(
        OD, OC, WSA, bias + 2048, 1.0f, 1024,
        1024, 16384, 1024, 0, 1024, 1048576, 4, 4);
    // 9) out[(l*16+n)][f] = attn_n[l][:] . Vt_n[f][:] -> d_out (f32)
    gemm_bt2<0, float><<<256, gblk, 0, stream>>>(
        WSB, WSA, out, nullptr, 1.0f, 1024,
        1024, 1024, 16384, 1048576, 1048576, 1024, 4, 4);
}